// Round 12
// baseline (231.693 us; speedup 1.0000x reference)
//
#include <hip/hip_runtime.h>
#include <hip/hip_bf16.h>

#define N_NODES 2048
#define N_EDGES 32768
#define BT      128           // B*T
#define TT      16
#define CH      32
#define E2      (N_EDGES + N_NODES)

static __device__ __forceinline__ unsigned pk2(float a, float b) {
    __hip_bfloat162 h2(__float2bfloat16(a), __float2bfloat16(b));   // a -> low 16
    return *reinterpret_cast<unsigned*>(&h2);
}

// ---------------- degree + attr segment sum ----------------
__global__ void deg_attr_kernel(const int* __restrict__ ei,
                                const float* __restrict__ ea,
                                int* __restrict__ deg, float* __restrict__ asum) {
    int e = blockIdx.x * 256 + threadIdx.x;
    if (e < N_EDGES) {
        int dst = ei[N_EDGES + e];
        atomicAdd(&deg[dst], 1);
        atomicAdd(&asum[dst], ea[e]);
    }
}

// ---------------- row_ptr scan (single wave) ----------------
__global__ void scan_kernel(const int* __restrict__ deg, int* __restrict__ rowp) {
    int lane = threadIdx.x;          // 64 threads
    int base = lane * 32;
    int loc[32];
    int s = 0;
    #pragma unroll
    for (int i = 0; i < 32; ++i) { loc[i] = s; s += deg[base + i] + 1; } // +1 self loop
    int inc = s;
    #pragma unroll
    for (int d = 1; d < 64; d <<= 1) {
        int v = __shfl_up(inc, d, 64);
        if (lane >= d) inc += v;
    }
    int excl = inc - s;
    #pragma unroll
    for (int i = 0; i < 32; ++i) rowp[base + i] = excl + loc[i];
    if (lane == 63) rowp[N_NODES] = inc;
}

// ---------------- scatter edges into CSR (by dst) ----------------
__global__ void scatter_kernel(const int* __restrict__ ei,
                               const float* __restrict__ ea,
                               const int* __restrict__ deg, const float* __restrict__ asum,
                               const int* __restrict__ rowp, int* __restrict__ fill,
                               int* __restrict__ col, float* __restrict__ attr_s) {
    int e = blockIdx.x * 256 + threadIdx.x;
    if (e >= E2) return;
    int src, dst; float a;
    if (e < N_EDGES) {
        src = ei[e]; dst = ei[N_EDGES + e]; a = ea[e];
    } else {
        int n = e - N_EDGES;
        src = n; dst = n;
        a = asum[n] / fmaxf((float)deg[n], 1.0f);   // mean edge attr
    }
    int pos = atomicAdd(&fill[dst], 1);
    col[rowp[dst] + pos]    = src;
    attr_s[rowp[dst] + pos] = a;
}

// ---------------- projection: xl -> packed bf16x2, ROW layout [n][128 bt][16 dw] ----------------
__global__ __launch_bounds__(256) void proj_kernel(
        const float* __restrict__ x,
        const float* __restrict__ Wl, const float* __restrict__ bl,
        unsigned* __restrict__ xlt) {      // [n][bt][c2] (row per (n,bt) = 64B)
    __shared__ float xs[128 * 32];     // [bt][f]
    __shared__ float wl[1024];
    int n = blockIdx.x;
    int tid = threadIdx.x;
    for (int i = tid; i < 1024; i += 256) wl[i] = Wl[i];
    #pragma unroll
    for (int i = 0; i < 16; ++i) {
        int e = i * 256 + tid;
        int bt = e >> 5, f = e & 31;
        xs[e] = x[((long)bt * N_NODES + n) * 32 + f];
    }
    __syncthreads();
    int c2  = tid & 15;
    int btl = tid >> 4;                // 0..15
    int c0 = 2 * c2, c1 = c0 + 1;
    float b0 = bl[c0], b1 = bl[c1];
    for (int i = 0; i < 8; ++i) {
        int bt = i * 16 + btl;
        float a0 = 0.f, a1 = 0.f;
        #pragma unroll
        for (int f = 0; f < 32; ++f) {
            float xv = xs[bt * 32 + f];           // broadcast read
            a0 = fmaf(xv, wl[f * 32 + c0], a0);
            a1 = fmaf(xv, wl[f * 32 + c1], a1);
        }
        xlt[((long)n * 128 + bt) * 16 + c2] = pk2(a0 + b0, a1 + b1);   // 64B row
    }
}

// ---------------- GAT + x-side GRU gates fused ----------------
// lane = bt; one wave = (node, 64 bt). Gather: per edge each lane fetches ITS OWN 64B
// row with 4x dwordx4 (vs r11's 16 strided dwords): 4x fewer VMEM issues, and the two
// bt-group waves touch disjoint 4KB halves (no shared L2 lines). col/attr pipelined 2
// edges ahead (index-load latency was serial per iter in r11). Wr/wih staged in LDS:
// kills the per-wave s_load/lgkmcnt stall chains in prologue/epilogue (r11: VALUBusy
// only 42% with ~50% of time unaccounted stall).
__global__ __launch_bounds__(256) void gat_kernel(
        const unsigned* __restrict__ xlt,   // [n][128][16] packed bf16x2 rows
        const float* __restrict__ x,        // [bt][n][f]
        const int* __restrict__ rowp, const int* __restrict__ col,
        const float* __restrict__ attr_s,
        const float* __restrict__ Wr, const float* __restrict__ br,
        const float* __restrict__ We, const float* __restrict__ att,
        const float* __restrict__ ob,
        const float* __restrict__ wih, const float* __restrict__ bih,
        __hip_bfloat16* __restrict__ gi) {   // [bt*N+n][96] bf16
    __shared__ float wr_s[1024];
    __shared__ float wi_s[3072];
    int tid = threadIdx.x;
    for (int i = tid; i < 1024; i += 256) wr_s[i] = Wr[i];
    for (int i = tid; i < 3072; i += 256) wi_s[i] = wih[i];
    __syncthreads();

    int wv = tid >> 6, lane = tid & 63;
    int task = blockIdx.x * 4 + wv;      // 4096 tasks = 2048 n x 2 btg
    int n   = task >> 1;
    int bt  = ((task & 1) << 6) | lane;

    // x row for this (bt,n): per-lane contiguous 128B
    float xf[32];
    {
        const float* xp = x + ((long)bt * N_NODES + n) * 32;
        #pragma unroll
        for (int f4 = 0; f4 < 8; ++f4) {
            float4 a = *(const float4*)(xp + f4 * 4);
            xf[f4*4+0]=a.x; xf[f4*4+1]=a.y; xf[f4*4+2]=a.z; xf[f4*4+3]=a.w;
        }
    }
    // xr = x @ Wr + br  (weights from LDS: broadcast reads, no SMEM stalls)
    float xrv[32];
    #pragma unroll
    for (int c = 0; c < 32; ++c) {
        float s = br[c];
        #pragma unroll
        for (int f = 0; f < 32; ++f) s = fmaf(xf[f], wr_s[f * 32 + c], s);
        xrv[c] = s;
    }

    float accv[32];
    #pragma unroll
    for (int c = 0; c < 32; ++c) accv[c] = 0.f;

    int beg = rowp[n];
    int end = rowp[n + 1];           // deg >= 1 always (self loop)
    float den = 0.f;

    // pipeline: data for edge j in up[]; indices for j+1 in (src1, av1)
    unsigned up[16];
    float av_j;
    int src1; float av1;
    {
        int s0 = col[beg]; av_j = attr_s[beg];
        const uint4* gp = (const uint4*)(xlt + ((long)s0 * 128 + bt) * 16);
        uint4 a = gp[0], b = gp[1], c = gp[2], d = gp[3];
        up[0]=a.x; up[1]=a.y; up[2]=a.z;  up[3]=a.w;
        up[4]=b.x; up[5]=b.y; up[6]=b.z;  up[7]=b.w;
        up[8]=c.x; up[9]=c.y; up[10]=c.z; up[11]=c.w;
        up[12]=d.x; up[13]=d.y; up[14]=d.z; up[15]=d.w;
        int j1 = (beg + 1 < end) ? beg + 1 : beg;
        src1 = col[j1]; av1 = attr_s[j1];
    }

    for (int j = beg; j < end; ++j) {
        // issue gather for edge j+1 (address ready from last iter)
        uint4 a, b, c4, d;
        {
            const uint4* gp = (const uint4*)(xlt + ((long)src1 * 128 + bt) * 16);
            a = gp[0]; b = gp[1]; c4 = gp[2]; d = gp[3];
        }
        // load indices for edge j+2 (full iteration of compute to cover latency)
        int j2 = (j + 2 < end) ? j + 2 : end - 1;
        int src2 = col[j2]; float av2 = attr_s[j2];

        // score from packed data (unpack on the fly)
        float av = av_j;
        float p0 = 0.f, p1 = 0.f, p2 = 0.f, p3 = 0.f;
        #pragma unroll
        for (int c2 = 0; c2 < 16; ++c2) {
            unsigned u = up[c2];
            float x0 = __uint_as_float(u << 16);
            float x1 = __uint_as_float(u & 0xffff0000u);
            int c = 2 * c2;
            float m0 = x0 + fmaf(av, We[c],     xrv[c]);
            float m1 = x1 + fmaf(av, We[c + 1], xrv[c + 1]);
            if (c2 & 1) { p2 = fmaf(att[c], fmaxf(m0, 0.2f * m0), p2);
                          p3 = fmaf(att[c + 1], fmaxf(m1, 0.2f * m1), p3); }
            else        { p0 = fmaf(att[c], fmaxf(m0, 0.2f * m0), p0);
                          p1 = fmaf(att[c + 1], fmaxf(m1, 0.2f * m1), p1); }
        }
        // scores bounded; softmax shift-invariant -> no max subtraction. Clamp = insurance.
        float p = fminf((p0 + p1) + (p2 + p3), 80.f);
        float w = __expf(p);
        den += w;
        #pragma unroll
        for (int c2 = 0; c2 < 16; ++c2) {
            unsigned u = up[c2];
            accv[2*c2]   = fmaf(w, __uint_as_float(u << 16),         accv[2*c2]);
            accv[2*c2+1] = fmaf(w, __uint_as_float(u & 0xffff0000u), accv[2*c2+1]);
        }
        // rotate pipeline regs
        up[0]=a.x; up[1]=a.y; up[2]=a.z;  up[3]=a.w;
        up[4]=b.x; up[5]=b.y; up[6]=b.z;  up[7]=b.w;
        up[8]=c4.x; up[9]=c4.y; up[10]=c4.z; up[11]=c4.w;
        up[12]=d.x; up[13]=d.y; up[14]=d.z; up[15]=d.w;
        av_j = av1; src1 = src2; av1 = av2;
    }
    float inv = 1.f / den;
    #pragma unroll
    for (int c = 0; c < 32; ++c) accv[c] = fmaf(accv[c], inv, ob[c]);   // h

    // gi = h @ wih^T + bih ; weights from LDS (broadcast ds_read, pipelines under FMA)
    __hip_bfloat16* gip = gi + ((long)bt * N_NODES + n) * 96;
    #pragma unroll
    for (int g8 = 0; g8 < 12; ++g8) {
        float s0 = bih[g8*8+0], s1 = bih[g8*8+1], s2 = bih[g8*8+2], s3 = bih[g8*8+3];
        float s4 = bih[g8*8+4], s5 = bih[g8*8+5], s6 = bih[g8*8+6], s7 = bih[g8*8+7];
        #pragma unroll
        for (int f = 0; f < 32; ++f) {
            float hf = accv[f];
            s0 = fmaf(hf, wi_s[(g8*8+0)*32+f], s0);
            s1 = fmaf(hf, wi_s[(g8*8+1)*32+f], s1);
            s2 = fmaf(hf, wi_s[(g8*8+2)*32+f], s2);
            s3 = fmaf(hf, wi_s[(g8*8+3)*32+f], s3);
            s4 = fmaf(hf, wi_s[(g8*8+4)*32+f], s4);
            s5 = fmaf(hf, wi_s[(g8*8+5)*32+f], s5);
            s6 = fmaf(hf, wi_s[(g8*8+6)*32+f], s6);
            s7 = fmaf(hf, wi_s[(g8*8+7)*32+f], s7);
        }
        uint4 v;
        v.x = pk2(s0, s1); v.y = pk2(s2, s3); v.z = pk2(s4, s5); v.w = pk2(s6, s7);
        *(uint4*)(gip + g8 * 8) = v;   // 8 bf16 = 16B store
    }
}

// ---------------- GRU recurrence: h-side only, 48 weights/lane, bf16 gi in ----------------
// one wave = one seq (b,n); lane = (c, fhalf): fhalf = lane>>5, c = lane&31.
__global__ __launch_bounds__(256) void gru_kernel(
        const float* __restrict__ whh, const float* __restrict__ bhh,
        const __hip_bfloat16* __restrict__ gi,   // [bt*N+n][96] bf16
        float* __restrict__ out) {               // [b,t,n,c]
    int tid  = threadIdx.x;
    int lane = tid & 63;
    int c    = lane & 31;
    int half = lane >> 5;
    int fbase = half << 4;
    int seq  = blockIdx.x * 4 + (tid >> 6);  // seq = b*2048 + n
    int b = seq >> 11;
    int n = seq & 2047;

    // 48 weights: rows {c, 32+c, 64+c} of whh, cols [fbase, fbase+16)
    float w0[16], w1[16], w2[16];
    #pragma unroll
    for (int k4 = 0; k4 < 4; ++k4) {
        float4 a0 = *(const float4*)&whh[( 0 + c) * 32 + fbase + k4 * 4];
        float4 a1 = *(const float4*)&whh[(32 + c) * 32 + fbase + k4 * 4];
        float4 a2 = *(const float4*)&whh[(64 + c) * 32 + fbase + k4 * 4];
        w0[k4*4+0]=a0.x; w0[k4*4+1]=a0.y; w0[k4*4+2]=a0.z; w0[k4*4+3]=a0.w;
        w1[k4*4+0]=a1.x; w1[k4*4+1]=a1.y; w1[k4*4+2]=a1.z; w1[k4*4+3]=a1.w;
        w2[k4*4+0]=a2.x; w2[k4*4+1]=a2.y; w2[k4*4+2]=a2.z; w2[k4*4+3]=a2.w;
    }
    float bh0 = half ? 0.f : bhh[c];        // count biases once (half0)
    float bh1 = half ? 0.f : bhh[32 + c];
    float bh2 = half ? 0.f : bhh[64 + c];

    const long GSTR = (long)N_NODES * 96;   // gi per-t stride
    long gbase = ((long)b * TT * N_NODES + n) * 96 + c;
    const long OSTR = (long)N_NODES * CH;
    long obase = ((long)b * TT * N_NODES + n) * CH + c;

    float hc = 0.f;
    float gr = __bfloat162float(gi[gbase]);
    float gz = __bfloat162float(gi[gbase + 32]);
    float gn = __bfloat162float(gi[gbase + 64]);
    #pragma unroll 1
    for (int t = 0; t < TT; ++t) {
        long gnx = gbase + (long)(t + 1) * GSTR;
        float grn = 0.f, gzn = 0.f, gnn = 0.f;
        if (t + 1 < TT) {
            grn = __bfloat162float(gi[gnx]);
            gzn = __bfloat162float(gi[gnx + 32]);
            gnn = __bfloat162float(gi[gnx + 64]);
        }
        float g0 = bh0, g1 = bh1, g2 = bh2;
        #pragma unroll
        for (int k = 0; k < 16; ++k) {
            float v = __shfl(hc, fbase + k, 64);   // h[f], sourced from half0 lanes
            g0 = fmaf(v, w0[k], g0);
            g1 = fmaf(v, w1[k], g1);
            g2 = fmaf(v, w2[k], g2);
        }
        float G0 = g0 + __shfl_xor(g0, 32, 64);    // hr + bhr  (full f-range)
        float G1 = g1 + __shfl_xor(g1, 32, 64);    // hz + bhz
        float G2 = g2 + __shfl_xor(g2, 32, 64);    // hn + bhn
        float r  = 1.f / (1.f + __expf(-(gr + G0)));
        float z  = 1.f / (1.f + __expf(-(gz + G1)));
        float a  = fmaf(r, G2, gn);
        float e2 = __expf(2.f * a);
        float nc = 1.f - 2.f / (e2 + 1.f);         // tanh, no inf/inf
        hc = (1.f - z) * nc + z * hc;
        if (half == 0) out[obase + (long)t * OSTR] = hc;   // coalesced 128B
        gr = grn; gz = gzn; gn = gnn;
    }
}

extern "C" void kernel_launch(void* const* d_in, const int* in_sizes, int n_in,
                              void* d_out, int out_size, void* d_ws, size_t ws_size,
                              hipStream_t stream) {
    const float* x    = (const float*)d_in[0];
    const int*   ei   = (const int*)d_in[1];
    const float* ea   = (const float*)d_in[2];
    const float* Wl   = (const float*)d_in[3];
    const float* bl   = (const float*)d_in[4];
    const float* Wr   = (const float*)d_in[5];
    const float* br   = (const float*)d_in[6];
    const float* We   = (const float*)d_in[7];
    const float* att  = (const float*)d_in[8];
    const float* ob   = (const float*)d_in[9];
    const float* wih  = (const float*)d_in[10];
    const float* whh  = (const float*)d_in[11];
    const float* bih  = (const float*)d_in[12];
    const float* bhh  = (const float*)d_in[13];
    float* out = (float*)d_out;

    // ---- workspace carve: small CSR metadata FIRST, then big arrays ----
    int*   deg  = (int*)d_ws;                  // N
    float* asum = (float*)(deg + N_NODES);     // N
    int*   fill = (int*)(asum + N_NODES);      // N
    int*   rowp = fill + N_NODES;              // N+1 (padded to +16)
    int*   col  = rowp + (N_NODES + 16);       // E2
    float* attr_s = (float*)(col + E2);        // E2
    unsigned* xlt = (unsigned*)(attr_s + E2);  // [N][128][16] packed = 16.8 MB
    xlt = (unsigned*)(((uintptr_t)xlt + 255) & ~(uintptr_t)255);
    __hip_bfloat16* gi = (__hip_bfloat16*)(xlt + (long)N_NODES * 16 * 128);  // 50.3 MB

    // zero the three counter arrays (contiguous: deg, asum, fill)
    hipMemsetAsync(deg, 0, 3 * N_NODES * sizeof(int), stream);

    deg_attr_kernel<<<N_EDGES / 256, 256, 0, stream>>>(ei, ea, deg, asum);
    scan_kernel<<<1, 64, 0, stream>>>(deg, rowp);
    scatter_kernel<<<(E2 + 255) / 256, 256, 0, stream>>>(ei, ea, deg, asum, rowp, fill, col, attr_s);
    proj_kernel<<<N_NODES, 256, 0, stream>>>(x, Wl, bl, xlt);
    gat_kernel<<<(N_NODES * 2) / 4, 256, 0, stream>>>(xlt, x, rowp, col, attr_s,
                                                      Wr, br, We, att, ob, wih, bih, gi);
    gru_kernel<<<(BT / TT * N_NODES) / 4, 256, 0, stream>>>(whh, bhh, gi, out);
}